// Round 1
// baseline (392.569 us; speedup 1.0000x reference)
//
#include <hip/hip_runtime.h>

// Problem constants (fixed by setup_inputs)
#define M_DIM 8192      // 4*2048
#define N_DIM 4096      // out_f
#define K_DIM 4096      // in_f
#define GROUPS_PER_ROW 128  // K/32

typedef short bf16x8 __attribute__((ext_vector_type(8)));
typedef float f32x4  __attribute__((ext_vector_type(4)));
typedef unsigned short u16x8 __attribute__((ext_vector_type(8)));

// ---------- helpers ----------
__device__ __forceinline__ unsigned short f2bf(float f) {
    unsigned int u = __float_as_uint(f);
    u += 0x7fffu + ((u >> 16) & 1u);   // round-to-nearest-even
    return (unsigned short)(u >> 16);
}

typedef const __attribute__((address_space(1))) void gvoid_t;
typedef __attribute__((address_space(3))) void lvoid_t;
__device__ __forceinline__ void gload_lds16(const void* g, void* l) {
    __builtin_amdgcn_global_load_lds((gvoid_t*)g, (lvoid_t*)l, 16, 0, 0);
}

// ---------- pass 1: dequantize weight -> bf16 [N][K] ----------
__global__ __launch_bounds__(256) void dequant_kernel(
        const float* __restrict__ w, const float* __restrict__ value,
        const float* __restrict__ mins, const float* __restrict__ maxs,
        unsigned short* __restrict__ wq) {
    int g = blockIdx.x * 256 + threadIdx.x;      // group id = o*128 + gi
    const float4* wp = reinterpret_cast<const float4*>(w + (size_t)g * 32);
    const float4* vp = reinterpret_cast<const float4*>(value + (size_t)g * 32);
    float4 wv[8], vv[8];
    #pragma unroll
    for (int j = 0; j < 8; j++) { wv[j] = wp[j]; vv[j] = vp[j]; }
    float mn = wv[0].x, mx = wv[0].x;
    #pragma unroll
    for (int j = 0; j < 8; j++) {
        mn = fminf(mn, fminf(fminf(wv[j].x, wv[j].y), fminf(wv[j].z, wv[j].w)));
        mx = fmaxf(mx, fmaxf(fmaxf(wv[j].x, wv[j].y), fmaxf(wv[j].z, wv[j].w)));
    }
    float w_min = mn * mins[g];
    float w_max = mx * maxs[g];
    float scale = fmaxf((w_max - w_min) * (1.0f / 255.0f), 1e-8f);
    float zp    = -w_min / scale;
    float rs    = 1.0f / scale;
    unsigned short ob[32];
    #pragma unroll
    for (int j = 0; j < 8; j++) {
        const float* wf = &wv[j].x;
        const float* vf = &vv[j].x;
        #pragma unroll
        for (int c = 0; c < 4; c++) {
            float ws_ = wf[c] * rs + zp + vf[c];
            float q   = fminf(fmaxf(rintf(ws_), 0.0f), 255.0f);
            ob[j * 4 + c] = f2bf(scale * (q - zp));
        }
    }
    u16x8* op = reinterpret_cast<u16x8*>(wq + (size_t)g * 32);
    #pragma unroll
    for (int j = 0; j < 4; j++) {
        u16x8 v;
        #pragma unroll
        for (int c = 0; c < 8; c++) v[c] = ob[j * 8 + c];
        op[j] = v;
    }
}

// ---------- pass 2: x f32 -> bf16 ----------
__global__ __launch_bounds__(256) void xconv_kernel(
        const float* __restrict__ x, unsigned short* __restrict__ xb) {
    int t = blockIdx.x * 256 + threadIdx.x;      // 8 elems / thread
    const float4* xp = reinterpret_cast<const float4*>(x) + (size_t)t * 2;
    float4 a = xp[0], b = xp[1];
    u16x8 v;
    v[0] = f2bf(a.x); v[1] = f2bf(a.y); v[2] = f2bf(a.z); v[3] = f2bf(a.w);
    v[4] = f2bf(b.x); v[5] = f2bf(b.y); v[6] = f2bf(b.z); v[7] = f2bf(b.w);
    reinterpret_cast<u16x8*>(xb)[t] = v;
}

// ---------- pass 3: bf16 MFMA GEMM-BT (m97 structure), fused bias ----------
// C[m][n] = sum_k A[m][k]*B[n][k] + bias[n];  A=[M][K] bf16, B=[N][K] bf16
#define BM 128
#define BN 128
#define BK 32
__global__ __launch_bounds__(256) void gemm_kernel(
        const unsigned short* __restrict__ A, const unsigned short* __restrict__ B,
        const float* __restrict__ bias, float* __restrict__ C) {
    __shared__ unsigned short lsA[BM * BK];
    __shared__ unsigned short lsB[BN * BK];

    const int tid  = threadIdx.x;
    const int lane = tid & 63;
    const int w    = tid >> 6;          // wave 0..3
    const int wr   = w >> 1, wc = w & 1;

    // XCD-aware bijective swizzle (grid=2048, 2048%8==0)
    const int nwg = gridDim.x;
    const int q8  = nwg >> 3;
    const int bid = blockIdx.x;
    const int swz = (bid & 7) * q8 + (bid >> 3);
    const int nbn = N_DIM / BN;         // 32
    const int bm  = swz / nbn;
    const int bn  = swz % nbn;

    f32x4 acc[4][4] = {};

    // per-lane staging element offsets within tile (8 bf16 = 16B per lane)
    const int idx0 = w * 1024 + lane * 8;      // q=0
    const int idx1 = idx0 + 512;               // q=1
    const int r0 = idx0 >> 5, kk0 = idx0 & 31;
    const int r1 = idx1 >> 5, kk1 = idx1 & 31;

    const unsigned short* Abase = A + (size_t)(bm * BM) * K_DIM;
    const unsigned short* Bbase = B + (size_t)(bn * BN) * K_DIM;

    const int la = (wr * 64 + (lane & 15)) * BK + (lane >> 4) * 8;
    const int lb = (wc * 64 + (lane & 15)) * BK + (lane >> 4) * 8;

    for (int k0 = 0; k0 < K_DIM; k0 += BK) {
        gload_lds16(Abase + (size_t)r0 * K_DIM + k0 + kk0, &lsA[idx0]);
        gload_lds16(Abase + (size_t)r1 * K_DIM + k0 + kk1, &lsA[idx1]);
        gload_lds16(Bbase + (size_t)r0 * K_DIM + k0 + kk0, &lsB[idx0]);
        gload_lds16(Bbase + (size_t)r1 * K_DIM + k0 + kk1, &lsB[idx1]);
        __syncthreads();

        bf16x8 af[4], bf_[4];
        #pragma unroll
        for (int i = 0; i < 4; i++) {
            af[i]  = *reinterpret_cast<const bf16x8*>(&lsA[la + i * 16 * BK]);
            bf_[i] = *reinterpret_cast<const bf16x8*>(&lsB[lb + i * 16 * BK]);
        }
        #pragma unroll
        for (int i = 0; i < 4; i++)
            #pragma unroll
            for (int j = 0; j < 4; j++)
                acc[i][j] = __builtin_amdgcn_mfma_f32_16x16x32_bf16(
                    af[i], bf_[j], acc[i][j], 0, 0, 0);
        __syncthreads();
    }

    // epilogue: C/D layout col=lane&15, row=(lane>>4)*4+r  [verified m89/m91]
    #pragma unroll
    for (int j = 0; j < 4; j++) {
        const int n  = bn * BN + wc * 64 + j * 16 + (lane & 15);
        const float bv = bias[n];
        #pragma unroll
        for (int i = 0; i < 4; i++) {
            const int m0 = bm * BM + wr * 64 + i * 16 + ((lane >> 4) << 2);
            #pragma unroll
            for (int r = 0; r < 4; r++)
                C[(size_t)(m0 + r) * N_DIM + n] = acc[i][j][r] + bv;
        }
    }
}

// ---------- fallback (ws too small): slow but correct, no workspace ----------
__global__ __launch_bounds__(256) void fallback_gemm(
        const float* __restrict__ x, const float* __restrict__ w,
        const float* __restrict__ value, const float* __restrict__ mins,
        const float* __restrict__ maxs, const float* __restrict__ bias,
        float* __restrict__ out) {
    const int n = blockIdx.x;                  // one output column per block
    __shared__ float wrow[K_DIM];
    const int tid = threadIdx.x;
    if (tid < GROUPS_PER_ROW) {
        const int g = tid;
        const float* wp = w + (size_t)n * K_DIM + g * 32;
        const float* vp = value + (size_t)n * K_DIM + g * 32;
        float tw[32];
        float mn = 1e30f, mx = -1e30f;
        #pragma unroll
        for (int j = 0; j < 32; j++) {
            tw[j] = wp[j]; mn = fminf(mn, tw[j]); mx = fmaxf(mx, tw[j]);
        }
        float wmin = mn * mins[n * GROUPS_PER_ROW + g];
        float wmax = mx * maxs[n * GROUPS_PER_ROW + g];
        float scale = fmaxf((wmax - wmin) * (1.0f / 255.0f), 1e-8f);
        float zp = -wmin / scale;
        #pragma unroll
        for (int j = 0; j < 32; j++) {
            float ws_ = tw[j] / scale + zp + vp[j];
            float q = fminf(fmaxf(rintf(ws_), 0.0f), 255.0f);
            wrow[g * 32 + j] = scale * (q - zp);
        }
    }
    __syncthreads();
    const float bv = bias[n];
    for (int m = tid; m < M_DIM; m += 256) {
        const float4* xr = reinterpret_cast<const float4*>(x + (size_t)m * K_DIM);
        const float4* wr4 = reinterpret_cast<const float4*>(wrow);
        float s = 0.f;
        for (int k = 0; k < K_DIM / 4; k++) {
            float4 a = xr[k], b = wr4[k];
            s += a.x * b.x + a.y * b.y + a.z * b.z + a.w * b.w;
        }
        out[(size_t)m * N_DIM + n] = s + bv;
    }
}

extern "C" void kernel_launch(void* const* d_in, const int* in_sizes, int n_in,
                              void* d_out, int out_size, void* d_ws, size_t ws_size,
                              hipStream_t stream) {
    const float* x     = (const float*)d_in[0];
    const float* ow    = (const float*)d_in[1];
    const float* value = (const float*)d_in[2];
    const float* mins  = (const float*)d_in[3];
    const float* maxs  = (const float*)d_in[4];
    const float* bias  = (const float*)d_in[5];
    float* out = (float*)d_out;

    const size_t xb_bytes = (size_t)M_DIM * K_DIM * 2;   // 67,108,864
    const size_t wb_bytes = (size_t)N_DIM * K_DIM * 2;   // 33,554,432

    if (ws_size >= xb_bytes + wb_bytes) {
        unsigned short* xb = (unsigned short*)d_ws;
        unsigned short* wb = (unsigned short*)((char*)d_ws + xb_bytes);

        // pass 1: dequant weight -> bf16 [N][K]
        dequant_kernel<<<(N_DIM * GROUPS_PER_ROW) / 256, 256, 0, stream>>>(
            ow, value, mins, maxs, wb);
        // pass 2: x -> bf16 [M][K]
        xconv_kernel<<<(M_DIM * K_DIM / 8) / 256, 256, 0, stream>>>(x, xb);
        // pass 3: MFMA GEMM + bias
        gemm_kernel<<<(M_DIM / BM) * (N_DIM / BN), 256, 0, stream>>>(
            xb, wb, bias, out);
    } else {
        fallback_gemm<<<N_DIM, 256, 0, stream>>>(x, ow, value, mins, maxs, bias, out);
    }
}

// Round 2
// 297.761 us; speedup vs baseline: 1.3184x; 1.3184x over previous
//
#include <hip/hip_runtime.h>

// Problem constants (fixed by setup_inputs)
#define M_DIM 8192      // 4*2048
#define N_DIM 4096      // out_f
#define K_DIM 4096      // in_f
#define GROUPS_PER_ROW 128
#define NT (K_DIM / 64) // 64 K-tiles of BK=64

typedef short bf16x8 __attribute__((ext_vector_type(8)));
typedef float f32x4  __attribute__((ext_vector_type(4)));
typedef unsigned short u16x8 __attribute__((ext_vector_type(8)));

__device__ __forceinline__ unsigned short f2bf(float f) {
    unsigned int u = __float_as_uint(f);
    u += 0x7fffu + ((u >> 16) & 1u);   // round-to-nearest-even
    return (unsigned short)(u >> 16);
}

typedef const __attribute__((address_space(1))) void gvoid_t;
typedef __attribute__((address_space(3))) void lvoid_t;
__device__ __forceinline__ void gload_lds16(const void* g, void* l) {
    __builtin_amdgcn_global_load_lds((gvoid_t*)g, (lvoid_t*)l, 16, 0, 0);
}

// ---------- pass 1: dequantize weight -> bf16 [N][K] ----------
__global__ __launch_bounds__(256) void dequant_kernel(
        const float* __restrict__ w, const float* __restrict__ value,
        const float* __restrict__ mins, const float* __restrict__ maxs,
        unsigned short* __restrict__ wq) {
    int g = blockIdx.x * 256 + threadIdx.x;
    const float4* wp = reinterpret_cast<const float4*>(w + (size_t)g * 32);
    const float4* vp = reinterpret_cast<const float4*>(value + (size_t)g * 32);
    float4 wv[8], vv[8];
    #pragma unroll
    for (int j = 0; j < 8; j++) { wv[j] = wp[j]; vv[j] = vp[j]; }
    float mn = wv[0].x, mx = wv[0].x;
    #pragma unroll
    for (int j = 0; j < 8; j++) {
        mn = fminf(mn, fminf(fminf(wv[j].x, wv[j].y), fminf(wv[j].z, wv[j].w)));
        mx = fmaxf(mx, fmaxf(fmaxf(wv[j].x, wv[j].y), fmaxf(wv[j].z, wv[j].w)));
    }
    float w_min = mn * mins[g];
    float w_max = mx * maxs[g];
    float scale = fmaxf((w_max - w_min) * (1.0f / 255.0f), 1e-8f);
    float zp    = -w_min / scale;
    float rs    = 1.0f / scale;
    unsigned short ob[32];
    #pragma unroll
    for (int j = 0; j < 8; j++) {
        const float* wf = &wv[j].x;
        const float* vf = &vv[j].x;
        #pragma unroll
        for (int c = 0; c < 4; c++) {
            float ws_ = wf[c] * rs + zp + vf[c];
            float q   = fminf(fmaxf(rintf(ws_), 0.0f), 255.0f);
            ob[j * 4 + c] = f2bf(scale * (q - zp));
        }
    }
    u16x8* op = reinterpret_cast<u16x8*>(wq + (size_t)g * 32);
    #pragma unroll
    for (int j = 0; j < 4; j++) {
        u16x8 v;
        #pragma unroll
        for (int c = 0; c < 8; c++) v[c] = ob[j * 8 + c];
        op[j] = v;
    }
}

// ---------- pass 2: x f32 -> bf16 ----------
__global__ __launch_bounds__(256) void xconv_kernel(
        const float* __restrict__ x, unsigned short* __restrict__ xb) {
    int t = blockIdx.x * 256 + threadIdx.x;
    const float4* xp = reinterpret_cast<const float4*>(x) + (size_t)t * 2;
    float4 a = xp[0], b = xp[1];
    u16x8 v;
    v[0] = f2bf(a.x); v[1] = f2bf(a.y); v[2] = f2bf(a.z); v[3] = f2bf(a.w);
    v[4] = f2bf(b.x); v[5] = f2bf(b.y); v[6] = f2bf(b.z); v[7] = f2bf(b.w);
    reinterpret_cast<u16x8*>(xb)[t] = v;
}

// ---------- pass 3: 256x256 8-wave 8-phase bf16 MFMA GEMM-BT + bias ----------
// C[m][n] = sum_k A[m][k]*B[n][k] + bias[n]
// LDS per buffer (64KB): A:[2 half][2 kk-panel][128 rows][32 bf16], B same at +32KB.
// st_16x32 swizzle: phys = logical ^ (((logical>>9)&1)<<5), involution, both sides.
__global__ __launch_bounds__(512, 2) void gemm_kernel(
        const unsigned short* __restrict__ A, const unsigned short* __restrict__ B,
        const float* __restrict__ bias, float* __restrict__ C) {
    __shared__ __align__(128) char lds[131072];

    const int tid  = threadIdx.x;
    const int lane = tid & 63;
    const int w    = tid >> 6;          // 0..7
    const int wr   = w >> 2;            // 0..1 (M split)
    const int wc   = w & 3;             // 0..3 (N split)
    const int l15  = lane & 15, lk = lane >> 4;

    // T1: bijective XCD swizzle (grid=512, 512%8==0)
    const int bid = blockIdx.x;
    const int swz = (bid & 7) * 64 + (bid >> 3);
    const int bm  = swz >> 4;           // 0..31
    const int bn  = swz & 15;           // 0..15

    // ds_read bases (swizzle folds to a per-thread constant: bit9 of row*64 = l15 bit3)
    const int swb   = ((l15 >> 3) & 1) << 5;
    const int rbyte = ((l15 * 64 + lk * 16) ^ swb);
    const int abase = wr * 16384 + rbyte;
    const int bbase = 32768 + (wc >> 1) * 16384 + (wc & 1) * 4096 + rbyte;

    // staging: each thread writes 2 linear 16B chunks per half-tile; source is
    // inverse-swizzled (involution) so swizzled reads return logical data
    const int c0  = tid * 16;
    const int c1  = 8192 + tid * 16;
    const int lb0 = c0 ^ (((c0 >> 9) & 1) << 5);
    const int lb1 = c1 ^ (((c1 >> 9) & 1) << 5);
    const int so0 = ((lb0 >> 6) & 127) * (K_DIM * 2) + (lb0 >> 13) * 64 + (lb0 & 63);
    const int so1 = ((lb1 >> 6) & 127) * (K_DIM * 2) + (lb1 >> 13) * 64 + (lb1 & 63);

    const char* srcA0 = (const char*)A + (size_t)(bm * 256 +   0) * (K_DIM * 2);
    const char* srcA1 = (const char*)A + (size_t)(bm * 256 + 128) * (K_DIM * 2);
    const char* srcB0 = (const char*)B + (size_t)(bn * 256 +   0) * (K_DIM * 2);
    const char* srcB1 = (const char*)B + (size_t)(bn * 256 + 128) * (K_DIM * 2);

    char* ldsc = (char*)lds;
    auto STAGE = [&](const char* src, int tt, int regionOff) {
        gload_lds16(src + (size_t)tt * 128 + so0, ldsc + regionOff + c0);
        gload_lds16(src + (size_t)tt * 128 + so1, ldsc + regionOff + c1);
    };

    f32x4 acc[8][4] = {};
    bf16x8 af[4][2], bf_[4][2];

    // prologue: tile0 all 4 half-tiles -> buf0; tile1 A halves -> buf1
    STAGE(srcA0, 0, 0);
    STAGE(srcA1, 0, 16384);
    STAGE(srcB0, 0, 32768);
    STAGE(srcB1, 0, 49152);
    STAGE(srcA0, 1, 65536);
    STAGE(srcA1, 1, 65536 + 16384);
    asm volatile("s_waitcnt vmcnt(4)" ::: "memory");
    __builtin_amdgcn_s_barrier();

    #pragma unroll 2
    for (int t = 0; t < NT; ++t) {
        const int bo  = (t & 1) << 16;
        const int bo2 = bo ^ 65536;

        // ---- phase 1: read A(mh=0) + B(nh=0); stage B_lo(t+1); MFMA (0,0) ----
        #pragma unroll
        for (int mi = 0; mi < 4; ++mi)
            #pragma unroll
            for (int kk = 0; kk < 2; ++kk)
                af[mi][kk] = *(const bf16x8*)(ldsc + bo + abase + mi * 1024 + kk * 8192);
        #pragma unroll
        for (int ni = 0; ni < 2; ++ni)
            #pragma unroll
            for (int kk = 0; kk < 2; ++kk)
                bf_[ni][kk] = *(const bf16x8*)(ldsc + bo + bbase + ni * 1024 + kk * 8192);
        if (t + 1 < NT) STAGE(srcB0, t + 1, bo2 + 32768);
        __builtin_amdgcn_s_barrier();
        asm volatile("s_waitcnt lgkmcnt(0)" ::: "memory");
        __builtin_amdgcn_sched_barrier(0);
        __builtin_amdgcn_s_setprio(1);
        #pragma unroll
        for (int mi = 0; mi < 4; ++mi)
            #pragma unroll
            for (int ni = 0; ni < 2; ++ni)
                #pragma unroll
                for (int kk = 0; kk < 2; ++kk)
                    acc[mi][ni] = __builtin_amdgcn_mfma_f32_16x16x32_bf16(
                        af[mi][kk], bf_[ni][kk], acc[mi][ni], 0, 0, 0);
        __builtin_amdgcn_s_setprio(0);
        __builtin_amdgcn_s_barrier();

        // ---- phase 2: read B(nh=1); stage B_hi(t+1); MFMA (0,1) ----
        #pragma unroll
        for (int ni = 2; ni < 4; ++ni)
            #pragma unroll
            for (int kk = 0; kk < 2; ++kk)
                bf_[ni][kk] = *(const bf16x8*)(ldsc + bo + bbase + ni * 1024 + kk * 8192);
        if (t + 1 < NT) STAGE(srcB1, t + 1, bo2 + 49152);
        __builtin_amdgcn_s_barrier();
        asm volatile("s_waitcnt lgkmcnt(0)" ::: "memory");
        __builtin_amdgcn_sched_barrier(0);
        __builtin_amdgcn_s_setprio(1);
        #pragma unroll
        for (int mi = 0; mi < 4; ++mi)
            #pragma unroll
            for (int ni = 2; ni < 4; ++ni)
                #pragma unroll
                for (int kk = 0; kk < 2; ++kk)
                    acc[mi][ni] = __builtin_amdgcn_mfma_f32_16x16x32_bf16(
                        af[mi][kk], bf_[ni][kk], acc[mi][ni], 0, 0, 0);
        __builtin_amdgcn_s_setprio(0);
        __builtin_amdgcn_s_barrier();

        // ---- phase 3: read A(mh=1); stage A_lo(t+2); MFMA (1,1) ----
        #pragma unroll
        for (int mi = 0; mi < 4; ++mi)
            #pragma unroll
            for (int kk = 0; kk < 2; ++kk)
                af[mi][kk] = *(const bf16x8*)(ldsc + bo + abase + 4096 + mi * 1024 + kk * 8192);
        if (t + 2 < NT) STAGE(srcA0, t + 2, bo + 0);
        __builtin_amdgcn_s_barrier();
        asm volatile("s_waitcnt lgkmcnt(0)" ::: "memory");
        __builtin_amdgcn_sched_barrier(0);
        __builtin_amdgcn_s_setprio(1);
        #pragma unroll
        for (int mi = 0; mi < 4; ++mi)
            #pragma unroll
            for (int ni = 2; ni < 4; ++ni)
                #pragma unroll
                for (int kk = 0; kk < 2; ++kk)
                    acc[mi + 4][ni] = __builtin_amdgcn_mfma_f32_16x16x32_bf16(
                        af[mi][kk], bf_[ni][kk], acc[mi + 4][ni], 0, 0, 0);
        __builtin_amdgcn_s_setprio(0);
        __builtin_amdgcn_s_barrier();

        // ---- phase 4: stage A_hi(t+2); MFMA (1,0); counted vmcnt ----
        if (t + 2 < NT) STAGE(srcA1, t + 2, bo + 16384);
        __builtin_amdgcn_s_barrier();
        __builtin_amdgcn_s_setprio(1);
        #pragma unroll
        for (int mi = 0; mi < 4; ++mi)
            #pragma unroll
            for (int ni = 0; ni < 2; ++ni)
                #pragma unroll
                for (int kk = 0; kk < 2; ++kk)
                    acc[mi + 4][ni] = __builtin_amdgcn_mfma_f32_16x16x32_bf16(
                        af[mi][kk], bf_[ni][kk], acc[mi + 4][ni], 0, 0, 0);
        __builtin_amdgcn_s_setprio(0);
        if (t + 2 < NT)      { asm volatile("s_waitcnt vmcnt(4)" ::: "memory"); }
        else if (t + 1 < NT) { asm volatile("s_waitcnt vmcnt(0)" ::: "memory"); }
        __builtin_amdgcn_s_barrier();
    }

    // epilogue: C/D layout col=lane&15, row=(lane>>4)*4+r
    float bv[4];
    #pragma unroll
    for (int ni = 0; ni < 4; ++ni)
        bv[ni] = bias[bn * 256 + wc * 64 + ni * 16 + l15];
    #pragma unroll
    for (int mi = 0; mi < 8; ++mi) {
        const int m0 = bm * 256 + wr * 128 + mi * 16 + lk * 4;
        #pragma unroll
        for (int ni = 0; ni < 4; ++ni) {
            const int n = bn * 256 + wc * 64 + ni * 16 + l15;
            #pragma unroll
            for (int r = 0; r < 4; ++r)
                C[(size_t)(m0 + r) * N_DIM + n] = acc[mi][ni][r] + bv[ni];
        }
    }
}

// ---------- fallback (ws too small): slow but correct ----------
__global__ __launch_bounds__(256) void fallback_gemm(
        const float* __restrict__ x, const float* __restrict__ w,
        const float* __restrict__ value, const float* __restrict__ mins,
        const float* __restrict__ maxs, const float* __restrict__ bias,
        float* __restrict__ out) {
    const int n = blockIdx.x;
    __shared__ float wrow[K_DIM];
    const int tid = threadIdx.x;
    if (tid < GROUPS_PER_ROW) {
        const int g = tid;
        const float* wp = w + (size_t)n * K_DIM + g * 32;
        const float* vp = value + (size_t)n * K_DIM + g * 32;
        float tw[32];
        float mn = 1e30f, mx = -1e30f;
        #pragma unroll
        for (int j = 0; j < 32; j++) {
            tw[j] = wp[j]; mn = fminf(mn, tw[j]); mx = fmaxf(mx, tw[j]);
        }
        float wmin = mn * mins[n * GROUPS_PER_ROW + g];
        float wmax = mx * maxs[n * GROUPS_PER_ROW + g];
        float scale = fmaxf((wmax - wmin) * (1.0f / 255.0f), 1e-8f);
        float zp = -wmin / scale;
        #pragma unroll
        for (int j = 0; j < 32; j++) {
            float ws_ = tw[j] / scale + zp + vp[j];
            float q = fminf(fmaxf(rintf(ws_), 0.0f), 255.0f);
            wrow[g * 32 + j] = scale * (q - zp);
        }
    }
    __syncthreads();
    const float bv = bias[n];
    for (int m = tid; m < M_DIM; m += 256) {
        const float4* xr = reinterpret_cast<const float4*>(x + (size_t)m * K_DIM);
        const float4* wr4 = reinterpret_cast<const float4*>(wrow);
        float s = 0.f;
        for (int k = 0; k < K_DIM / 4; k++) {
            float4 a = xr[k], b = wr4[k];
            s += a.x * b.x + a.y * b.y + a.z * b.z + a.w * b.w;
        }
        out[(size_t)m * N_DIM + n] = s + bv;
    }
}

extern "C" void kernel_launch(void* const* d_in, const int* in_sizes, int n_in,
                              void* d_out, int out_size, void* d_ws, size_t ws_size,
                              hipStream_t stream) {
    const float* x     = (const float*)d_in[0];
    const float* ow    = (const float*)d_in[1];
    const float* value = (const float*)d_in[2];
    const float* mins  = (const float*)d_in[3];
    const float* maxs  = (const float*)d_in[4];
    const float* bias  = (const float*)d_in[5];
    float* out = (float*)d_out;

    const size_t xb_bytes = (size_t)M_DIM * K_DIM * 2;
    const size_t wb_bytes = (size_t)N_DIM * K_DIM * 2;

    if (ws_size >= xb_bytes + wb_bytes) {
        unsigned short* xb = (unsigned short*)d_ws;
        unsigned short* wb = (unsigned short*)((char*)d_ws + xb_bytes);

        dequant_kernel<<<(N_DIM * GROUPS_PER_ROW) / 256, 256, 0, stream>>>(
            ow, value, mins, maxs, wb);
        xconv_kernel<<<(M_DIM * K_DIM / 8) / 256, 256, 0, stream>>>(x, xb);
        gemm_kernel<<<(M_DIM / 256) * (N_DIM / 256), 512, 0, stream>>>(
            xb, wb, bias, out);
    } else {
        fallback_gemm<<<N_DIM, 256, 0, stream>>>(x, ow, value, mins, maxs, bias, out);
    }
}

// Round 4
// 288.518 us; speedup vs baseline: 1.3606x; 1.0320x over previous
//
#include <hip/hip_runtime.h>

// Problem constants (fixed by setup_inputs)
#define M_DIM 8192      // 4*2048
#define N_DIM 4096      // out_f
#define K_DIM 4096      // in_f
#define GROUPS_PER_ROW 128
#define NT (K_DIM / 64) // 64 K-tiles of BK=64

typedef short bf16x8 __attribute__((ext_vector_type(8)));
typedef float f32x4  __attribute__((ext_vector_type(4)));
typedef unsigned short u16x8 __attribute__((ext_vector_type(8)));

__device__ __forceinline__ unsigned short f2bf(float f) {
    unsigned int u = __float_as_uint(f);
    u += 0x7fffu + ((u >> 16) & 1u);   // round-to-nearest-even
    return (unsigned short)(u >> 16);
}

typedef const __attribute__((address_space(1))) void gvoid_t;
typedef __attribute__((address_space(3))) void lvoid_t;
__device__ __forceinline__ void gload_lds16(const void* g, void* l) {
    __builtin_amdgcn_global_load_lds((gvoid_t*)g, (lvoid_t*)l, 16, 0, 0);
}

// ---------- pass 1: dequantize weight -> bf16 [N][K] ----------
__global__ __launch_bounds__(256) void dequant_kernel(
        const float* __restrict__ w, const float* __restrict__ value,
        const float* __restrict__ mins, const float* __restrict__ maxs,
        unsigned short* __restrict__ wq) {
    int g = blockIdx.x * 256 + threadIdx.x;
    const float4* wp = reinterpret_cast<const float4*>(w + (size_t)g * 32);
    const float4* vp = reinterpret_cast<const float4*>(value + (size_t)g * 32);
    float4 wv[8], vv[8];
    #pragma unroll
    for (int j = 0; j < 8; j++) { wv[j] = wp[j]; vv[j] = vp[j]; }
    float mn = wv[0].x, mx = wv[0].x;
    #pragma unroll
    for (int j = 0; j < 8; j++) {
        mn = fminf(mn, fminf(fminf(wv[j].x, wv[j].y), fminf(wv[j].z, wv[j].w)));
        mx = fmaxf(mx, fmaxf(fmaxf(wv[j].x, wv[j].y), fmaxf(wv[j].z, wv[j].w)));
    }
    float w_min = mn * mins[g];
    float w_max = mx * maxs[g];
    float scale = fmaxf((w_max - w_min) * (1.0f / 255.0f), 1e-8f);
    float zp    = -w_min / scale;
    float rs    = 1.0f / scale;
    unsigned short ob[32];
    #pragma unroll
    for (int j = 0; j < 8; j++) {
        const float* wf = &wv[j].x;
        const float* vf = &vv[j].x;
        #pragma unroll
        for (int c = 0; c < 4; c++) {
            float ws_ = wf[c] * rs + zp + vf[c];
            float q   = fminf(fmaxf(rintf(ws_), 0.0f), 255.0f);
            ob[j * 4 + c] = f2bf(scale * (q - zp));
        }
    }
    u16x8* op = reinterpret_cast<u16x8*>(wq + (size_t)g * 32);
    #pragma unroll
    for (int j = 0; j < 4; j++) {
        u16x8 v;
        #pragma unroll
        for (int c = 0; c < 8; c++) v[c] = ob[j * 8 + c];
        op[j] = v;
    }
}

// ---------- pass 2: x f32 -> bf16 ----------
__global__ __launch_bounds__(256) void xconv_kernel(
        const float* __restrict__ x, unsigned short* __restrict__ xb) {
    int t = blockIdx.x * 256 + threadIdx.x;
    const float4* xp = reinterpret_cast<const float4*>(x) + (size_t)t * 2;
    float4 a = xp[0], b = xp[1];
    u16x8 v;
    v[0] = f2bf(a.x); v[1] = f2bf(a.y); v[2] = f2bf(a.z); v[3] = f2bf(a.w);
    v[4] = f2bf(b.x); v[5] = f2bf(b.y); v[6] = f2bf(b.z); v[7] = f2bf(b.w);
    reinterpret_cast<u16x8*>(xb)[t] = v;
}

// ---------- pass 3: 256x256 8-wave 3-phase bf16 MFMA GEMM-BT + bias ----------
// C[m][n] = sum_k A[m][k]*B[n][k] + bias[n]  (16x16x32 MFMA, round-2-verified layout)
// LDS per buffer (64KB): A:[2 half][2 kk-panel][128 rows][32 bf16], B same at +32KB.
// st_16x32 swizzle: phys = logical ^ (((logical>>9)&1)<<5), involution, both sides.
// NO manual lgkmcnt drains: compiler emits fine-grained lgkmcnt(N) so MFMA overlaps
// LDS servicing of later reads. sched_barrier(0) after each s_barrier pins memory
// ops to their phase (prevents read-hoist above the staging-completion barrier).
__global__ __launch_bounds__(512, 2) void gemm_kernel(
        const unsigned short* __restrict__ A, const unsigned short* __restrict__ B,
        const float* __restrict__ bias, float* __restrict__ C) {
    __shared__ __align__(128) char lds[131072];

    const int tid  = threadIdx.x;
    const int lane = tid & 63;
    const int w    = tid >> 6;          // 0..7
    const int wr   = w >> 2;            // 0..1 (M split)
    const int wc   = w & 3;             // 0..3 (N split)
    const int l15  = lane & 15, lk = lane >> 4;

    // T1: bijective XCD swizzle (grid=512, 512%8==0)
    const int bid = blockIdx.x;
    const int swz = (bid & 7) * 64 + (bid >> 3);
    const int bm  = swz >> 4;           // 0..31
    const int bn  = swz & 15;           // 0..15

    // ds_read bases (swizzle folds to a per-thread constant: bit9 of row*64 = l15 bit3)
    const int swb   = ((l15 >> 3) & 1) << 5;
    const int rbyte = ((l15 * 64 + lk * 16) ^ swb);
    const int abase = wr * 16384 + rbyte;
    const int bbase = 32768 + (wc >> 1) * 16384 + (wc & 1) * 4096 + rbyte;

    // staging: linear 16B chunks; source address inverse-swizzled (involution)
    const int c0  = tid * 16;
    const int c1  = 8192 + tid * 16;
    const int lb0 = c0 ^ (((c0 >> 9) & 1) << 5);
    const int lb1 = c1 ^ (((c1 >> 9) & 1) << 5);
    const int so0 = ((lb0 >> 6) & 127) * (K_DIM * 2) + (lb0 >> 13) * 64 + (lb0 & 63);
    const int so1 = ((lb1 >> 6) & 127) * (K_DIM * 2) + (lb1 >> 13) * 64 + (lb1 & 63);

    const char* srcA0 = (const char*)A + (size_t)(bm * 256 +   0) * (K_DIM * 2);
    const char* srcA1 = (const char*)A + (size_t)(bm * 256 + 128) * (K_DIM * 2);
    const char* srcB0 = (const char*)B + (size_t)(bn * 256 +   0) * (K_DIM * 2);
    const char* srcB1 = (const char*)B + (size_t)(bn * 256 + 128) * (K_DIM * 2);

    char* ldsc = (char*)lds;
    auto STAGE = [&](const char* src, int tt, int regionOff) {
        gload_lds16(src + (size_t)tt * 128 + so0, ldsc + regionOff + c0);
        gload_lds16(src + (size_t)tt * 128 + so1, ldsc + regionOff + c1);
    };

    f32x4 acc[8][4] = {};
    bf16x8 af[4][2], bf_[4][2];

    // prologue: tile0 all 4 half-tiles -> buf0; tile1 A halves -> buf1
    STAGE(srcA0, 0, 0);
    STAGE(srcA1, 0, 16384);
    STAGE(srcB0, 0, 32768);
    STAGE(srcB1, 0, 49152);
    STAGE(srcA0, 1, 65536);
    STAGE(srcA1, 1, 65536 + 16384);
    asm volatile("s_waitcnt vmcnt(4)" ::: "memory");
    __builtin_amdgcn_s_barrier();
    __builtin_amdgcn_sched_barrier(0);

    #pragma unroll 2
    for (int t = 0; t < NT; ++t) {
        const int bo  = (t & 1) << 16;
        const int bo2 = bo ^ 65536;

        // ---- phase 1: read A(mh=0) + B(nh=0); stage B_lo(t+1); MFMA Q00 ----
        #pragma unroll
        for (int mi = 0; mi < 4; ++mi)
            #pragma unroll
            for (int kk = 0; kk < 2; ++kk)
                af[mi][kk] = *(const bf16x8*)(ldsc + bo + abase + mi * 1024 + kk * 8192);
        #pragma unroll
        for (int ni = 0; ni < 2; ++ni)
            #pragma unroll
            for (int kk = 0; kk < 2; ++kk)
                bf_[ni][kk] = *(const bf16x8*)(ldsc + bo + bbase + ni * 1024 + kk * 8192);
        if (t + 1 < NT) STAGE(srcB0, t + 1, bo2 + 32768);
        __builtin_amdgcn_s_barrier();
        __builtin_amdgcn_sched_barrier(0);
        __builtin_amdgcn_s_setprio(1);
        #pragma unroll
        for (int mi = 0; mi < 4; ++mi)
            #pragma unroll
            for (int ni = 0; ni < 2; ++ni)
                #pragma unroll
                for (int kk = 0; kk < 2; ++kk)
                    acc[mi][ni] = __builtin_amdgcn_mfma_f32_16x16x32_bf16(
                        af[mi][kk], bf_[ni][kk], acc[mi][ni], 0, 0, 0);
        __builtin_amdgcn_s_setprio(0);

        // ---- phase 2: read B(nh=1); stage B_hi(t+1); MFMA Q01 ----
        #pragma unroll
        for (int ni = 2; ni < 4; ++ni)
            #pragma unroll
            for (int kk = 0; kk < 2; ++kk)
                bf_[ni][kk] = *(const bf16x8*)(ldsc + bo + bbase + ni * 1024 + kk * 8192);
        if (t + 1 < NT) STAGE(srcB1, t + 1, bo2 + 49152);
        __builtin_amdgcn_s_barrier();
        __builtin_amdgcn_sched_barrier(0);
        __builtin_amdgcn_s_setprio(1);
        #pragma unroll
        for (int mi = 0; mi < 4; ++mi)
            #pragma unroll
            for (int ni = 2; ni < 4; ++ni)
                #pragma unroll
                for (int kk = 0; kk < 2; ++kk)
                    acc[mi][ni] = __builtin_amdgcn_mfma_f32_16x16x32_bf16(
                        af[mi][kk], bf_[ni][kk], acc[mi][ni], 0, 0, 0);
        __builtin_amdgcn_s_setprio(0);

        // ---- phase 3: read A(mh=1); stage A_lo+A_hi(t+2); MFMA Q11+Q10; vmcnt ----
        #pragma unroll
        for (int mi = 0; mi < 4; ++mi)
            #pragma unroll
            for (int kk = 0; kk < 2; ++kk)
                af[mi][kk] = *(const bf16x8*)(ldsc + bo + abase + 4096 + mi * 1024 + kk * 8192);
        if (t + 2 < NT) {
            STAGE(srcA0, t + 2, bo + 0);
            STAGE(srcA1, t + 2, bo + 16384);
        }
        __builtin_amdgcn_s_barrier();
        __builtin_amdgcn_sched_barrier(0);
        __builtin_amdgcn_s_setprio(1);
        #pragma unroll
        for (int mi = 0; mi < 4; ++mi)
            #pragma unroll
            for (int ni = 2; ni < 4; ++ni)
                #pragma unroll
                for (int kk = 0; kk < 2; ++kk)
                    acc[mi + 4][ni] = __builtin_amdgcn_mfma_f32_16x16x32_bf16(
                        af[mi][kk], bf_[ni][kk], acc[mi + 4][ni], 0, 0, 0);
        #pragma unroll
        for (int mi = 0; mi < 4; ++mi)
            #pragma unroll
            for (int ni = 0; ni < 2; ++ni)
                #pragma unroll
                for (int kk = 0; kk < 2; ++kk)
                    acc[mi + 4][ni] = __builtin_amdgcn_mfma_f32_16x16x32_bf16(
                        af[mi][kk], bf_[ni][kk], acc[mi + 4][ni], 0, 0, 0);
        __builtin_amdgcn_s_setprio(0);
        if (t + 2 < NT)      { asm volatile("s_waitcnt vmcnt(4)" ::: "memory"); }
        else if (t + 1 < NT) { asm volatile("s_waitcnt vmcnt(0)" ::: "memory"); }
        __builtin_amdgcn_s_barrier();
        __builtin_amdgcn_sched_barrier(0);
    }

    // epilogue: C/D layout col=lane&15, row=(lane>>4)*4+r
    float bv[4];
    #pragma unroll
    for (int ni = 0; ni < 4; ++ni)
        bv[ni] = bias[bn * 256 + wc * 64 + ni * 16 + l15];
    #pragma unroll
    for (int mi = 0; mi < 8; ++mi) {
        const int m0 = bm * 256 + wr * 128 + mi * 16 + lk * 4;
        #pragma unroll
        for (int ni = 0; ni < 4; ++ni) {
            const int n = bn * 256 + wc * 64 + ni * 16 + l15;
            #pragma unroll
            for (int r = 0; r < 4; ++r)
                C[(size_t)(m0 + r) * N_DIM + n] = acc[mi][ni][r] + bv[ni];
        }
    }
}

// ---------- fallback (ws too small): slow but correct ----------
__global__ __launch_bounds__(256) void fallback_gemm(
        const float* __restrict__ x, const float* __restrict__ w,
        const float* __restrict__ value, const float* __restrict__ mins,
        const float* __restrict__ maxs, const float* __restrict__ bias,
        float* __restrict__ out) {
    const int n = blockIdx.x;
    __shared__ float wrow[K_DIM];
    const int tid = threadIdx.x;
    if (tid < GROUPS_PER_ROW) {
        const int g = tid;
        const float* wp = w + (size_t)n * K_DIM + g * 32;
        const float* vp = value + (size_t)n * K_DIM + g * 32;
        float tw[32];
        float mn = 1e30f, mx = -1e30f;
        #pragma unroll
        for (int j = 0; j < 32; j++) {
            tw[j] = wp[j]; mn = fminf(mn, tw[j]); mx = fmaxf(mx, tw[j]);
        }
        float wmin = mn * mins[n * GROUPS_PER_ROW + g];
        float wmax = mx * maxs[n * GROUPS_PER_ROW + g];
        float scale = fmaxf((wmax - wmin) * (1.0f / 255.0f), 1e-8f);
        float zp = -wmin / scale;
        #pragma unroll
        for (int j = 0; j < 32; j++) {
            float ws_ = tw[j] / scale + zp + vp[j];
            float q = fminf(fmaxf(rintf(ws_), 0.0f), 255.0f);
            wrow[g * 32 + j] = scale * (q - zp);
        }
    }
    __syncthreads();
    const float bv = bias[n];
    for (int m = tid; m < M_DIM; m += 256) {
        const float4* xr = reinterpret_cast<const float4*>(x + (size_t)m * K_DIM);
        const float4* wr4 = reinterpret_cast<const float4*>(wrow);
        float s = 0.f;
        for (int k = 0; k < K_DIM / 4; k++) {
            float4 a = xr[k], b = wr4[k];
            s += a.x * b.x + a.y * b.y + a.z * b.z + a.w * b.w;
        }
        out[(size_t)m * N_DIM + n] = s + bv;
    }
}

extern "C" void kernel_launch(void* const* d_in, const int* in_sizes, int n_in,
                              void* d_out, int out_size, void* d_ws, size_t ws_size,
                              hipStream_t stream) {
    const float* x     = (const float*)d_in[0];
    const float* ow    = (const float*)d_in[1];
    const float* value = (const float*)d_in[2];
    const float* mins  = (const float*)d_in[3];
    const float* maxs  = (const float*)d_in[4];
    const float* bias  = (const float*)d_in[5];
    float* out = (float*)d_out;

    const size_t xb_bytes = (size_t)M_DIM * K_DIM * 2;
    const size_t wb_bytes = (size_t)N_DIM * K_DIM * 2;

    if (ws_size >= xb_bytes + wb_bytes) {
        unsigned short* xb = (unsigned short*)d_ws;
        unsigned short* wb = (unsigned short*)((char*)d_ws + xb_bytes);

        dequant_kernel<<<(N_DIM * GROUPS_PER_ROW) / 256, 256, 0, stream>>>(
            ow, value, mins, maxs, wb);
        xconv_kernel<<<(M_DIM * K_DIM / 8) / 256, 256, 0, stream>>>(x, xb);
        gemm_kernel<<<(M_DIM / 256) * (N_DIM / 256), 512, 0, stream>>>(
            xb, wb, bias, out);
    } else {
        fallback_gemm<<<N_DIM, 256, 0, stream>>>(x, ow, value, mins, maxs, bias, out);
    }
}